// Round 1
// 378.834 us; speedup vs baseline: 1.0037x; 1.0037x over previous
//
#include <hip/hip_runtime.h>

#define HDIM 1024
#define BDIM 32
#define LDIM 1024

// ws layout (floats): u1[0:H], u2[H:2H], vbar[2H : 2H+B*H], logits[2H+B*H : +B*L]

__device__ __forceinline__ float4 fma4(float s, float4 v, float4 a) {
    a.x += s * v.x; a.y += s * v.y; a.z += s * v.z; a.w += s * v.w;
    return a;
}

// u1[h] = sum_o W[o,h]*w1[o]; u2[h] = sum_o W[o,h]*w2[o]. Coalesced row reads.
__global__ __launch_bounds__(256) void k_u12(const float4* __restrict__ W4,
                                             const float* __restrict__ mlp_w,
                                             float* __restrict__ u1,
                                             float* __restrict__ u2) {
    int t  = threadIdx.x;            // float4 index within a row, [0,256)
    int o0 = blockIdx.x * 16;        // 64 blocks x 16 rows
    float4 s1 = make_float4(0.f, 0.f, 0.f, 0.f);
    float4 s2 = make_float4(0.f, 0.f, 0.f, 0.f);
    #pragma unroll 4
    for (int o = o0; o < o0 + 16; ++o) {
        float4 w = W4[o * 256 + t];
        float c1 = mlp_w[o];
        float c2 = mlp_w[HDIM + o];
        s1.x += w.x * c1; s1.y += w.y * c1; s1.z += w.z * c1; s1.w += w.w * c1;
        s2.x += w.x * c2; s2.y += w.y * c2; s2.z += w.z * c2; s2.w += w.w * c2;
    }
    int h = t * 4;
    atomicAdd(&u1[h + 0], s1.x); atomicAdd(&u1[h + 1], s1.y);
    atomicAdd(&u1[h + 2], s1.z); atomicAdd(&u1[h + 3], s1.w);
    atomicAdd(&u2[h + 0], s2.x); atomicAdd(&u2[h + 1], s2.y);
    atomicAdd(&u2[h + 2], s2.z); atomicAdd(&u2[h + 3], s2.w);
}

// logits[row] = relu(q[row]·u1 + k[row]·u2 + b).
// 8 rows per wave; loads batched 16-deep into registers for MLP.
__global__ __launch_bounds__(256, 4) void k_logits(const float4* __restrict__ q,
                                                   const float4* __restrict__ k,
                                                   const float4* __restrict__ u1v,
                                                   const float4* __restrict__ u2v,
                                                   const float* __restrict__ mlp_b,
                                                   float* __restrict__ logits) {
    int t = threadIdx.x;
    int lane = t & 63, wave = t >> 6;
    float4 a1[4], a2[4];
    #pragma unroll
    for (int i = 0; i < 4; ++i) {
        a1[i] = u1v[lane + 64 * i];
        a2[i] = u2v[lane + 64 * i];
    }
    float bias = mlp_b[0];
    long long wid  = (long long)blockIdx.x * 4 + wave;  // [0, 4096)
    long long row0 = wid * 8;                           // [0, 32768) step 8
    const float4* qb = q + row0 * 256 + lane;
    const float4* kb = k + row0 * 256 + lane;

    float acc[8];
    #pragma unroll
    for (int g = 0; g < 2; ++g) {
        float4 x[4][4];
        // batch-issue 16 q loads (4 rows x 4 float4) before consuming
        #pragma unroll
        for (int r = 0; r < 4; ++r)
            #pragma unroll
            for (int i = 0; i < 4; ++i)
                x[r][i] = qb[(g * 4 + r) * 256 + 64 * i];
        #pragma unroll
        for (int r = 0; r < 4; ++r) {
            float s = 0.f;
            #pragma unroll
            for (int i = 0; i < 4; ++i)
                s += x[r][i].x * a1[i].x + x[r][i].y * a1[i].y +
                     x[r][i].z * a1[i].z + x[r][i].w * a1[i].w;
            acc[g * 4 + r] = s;
        }
        // batch-issue 16 k loads, reusing the buffer registers
        #pragma unroll
        for (int r = 0; r < 4; ++r)
            #pragma unroll
            for (int i = 0; i < 4; ++i)
                x[r][i] = kb[(g * 4 + r) * 256 + 64 * i];
        #pragma unroll
        for (int r = 0; r < 4; ++r) {
            float s = acc[g * 4 + r];
            #pragma unroll
            for (int i = 0; i < 4; ++i)
                s += x[r][i].x * a2[i].x + x[r][i].y * a2[i].y +
                     x[r][i].z * a2[i].z + x[r][i].w * a2[i].w;
            acc[g * 4 + r] = s;
        }
    }
    // 8 independent reduce chains; row-inner loop lets them pipeline
    #pragma unroll
    for (int off = 32; off > 0; off >>= 1)
        #pragma unroll
        for (int r = 0; r < 8; ++r)
            acc[r] += __shfl_down(acc[r], off, 64);
    if (lane == 0) {
        float4 o0, o1;
        float v;
        v = acc[0] + bias; o0.x = v > 0.f ? v : 0.f;
        v = acc[1] + bias; o0.y = v > 0.f ? v : 0.f;
        v = acc[2] + bias; o0.z = v > 0.f ? v : 0.f;
        v = acc[3] + bias; o0.w = v > 0.f ? v : 0.f;
        v = acc[4] + bias; o1.x = v > 0.f ? v : 0.f;
        v = acc[5] + bias; o1.y = v > 0.f ? v : 0.f;
        v = acc[6] + bias; o1.z = v > 0.f ? v : 0.f;
        v = acc[7] + bias; o1.w = v > 0.f ? v : 0.f;
        float4* dst = (float4*)(logits + row0);
        dst[0] = o0;
        dst[1] = o1;
    }
}

__global__ __launch_bounds__(256) void k_softmax(const float* __restrict__ logits,
                                                 float* __restrict__ score) {
    __shared__ float sm[4];
    __shared__ float ss[4];
    int b = blockIdx.x;
    int t = threadIdx.x;
    int wave = t >> 6, lane = t & 63;
    float4 v = ((const float4*)(logits + b * LDIM))[t];
    float m = fmaxf(fmaxf(v.x, v.y), fmaxf(v.z, v.w));
    #pragma unroll
    for (int off = 32; off > 0; off >>= 1)
        m = fmaxf(m, __shfl_down(m, off, 64));
    if (lane == 0) sm[wave] = m;
    __syncthreads();
    float M = fmaxf(fmaxf(sm[0], sm[1]), fmaxf(sm[2], sm[3]));
    float4 e;
    e.x = __expf(v.x - M); e.y = __expf(v.y - M);
    e.z = __expf(v.z - M); e.w = __expf(v.w - M);
    float s = e.x + e.y + e.z + e.w;
    #pragma unroll
    for (int off = 32; off > 0; off >>= 1)
        s += __shfl_down(s, off, 64);
    if (lane == 0) ss[wave] = s;
    __syncthreads();
    float inv = 1.f / (ss[0] + ss[1] + ss[2] + ss[3]);
    float4 o;
    o.x = e.x * inv; o.y = e.y * inv; o.z = e.z * inv; o.w = e.w * inv;
    ((float4*)(score + b * LDIM))[t] = o;
}

// vbar[b,h] = sum_l score[b,l] * value[b,l,h]. 8 value rows in flight per thread.
__global__ __launch_bounds__(256, 4) void k_vbar(const float4* __restrict__ value,
                                                 const float* __restrict__ score,
                                                 float* __restrict__ vbar) {
    int b  = blockIdx.x >> 4;        // [0,32)
    int lc = blockIdx.x & 15;        // 16 l-chunks of 64
    int t  = threadIdx.x;
    const float4* vrow = value + ((long long)b * LDIM + lc * 64) * 256 + t;
    const float*  sc   = score + b * LDIM + lc * 64;
    float4 A0 = make_float4(0.f, 0.f, 0.f, 0.f);
    float4 A1 = make_float4(0.f, 0.f, 0.f, 0.f);
    float4 A2 = make_float4(0.f, 0.f, 0.f, 0.f);
    float4 A3 = make_float4(0.f, 0.f, 0.f, 0.f);
    #pragma unroll 2
    for (int l = 0; l < 64; l += 8) {
        float4 v0 = vrow[(l + 0) * 256];
        float4 v1 = vrow[(l + 1) * 256];
        float4 v2 = vrow[(l + 2) * 256];
        float4 v3 = vrow[(l + 3) * 256];
        float4 v4 = vrow[(l + 4) * 256];
        float4 v5 = vrow[(l + 5) * 256];
        float4 v6 = vrow[(l + 6) * 256];
        float4 v7 = vrow[(l + 7) * 256];
        float s0 = sc[l + 0], s1 = sc[l + 1], s2 = sc[l + 2], s3 = sc[l + 3];
        float s4 = sc[l + 4], s5 = sc[l + 5], s6 = sc[l + 6], s7 = sc[l + 7];
        A0 = fma4(s0, v0, A0);
        A1 = fma4(s1, v1, A1);
        A2 = fma4(s2, v2, A2);
        A3 = fma4(s3, v3, A3);
        A0 = fma4(s4, v4, A0);
        A1 = fma4(s5, v5, A1);
        A2 = fma4(s6, v6, A2);
        A3 = fma4(s7, v7, A3);
    }
    float4 r;
    r.x = (A0.x + A1.x) + (A2.x + A3.x);
    r.y = (A0.y + A1.y) + (A2.y + A3.y);
    r.z = (A0.z + A1.z) + (A2.z + A3.z);
    r.w = (A0.w + A1.w) + (A2.w + A3.w);
    float* dst = vbar + b * HDIM + t * 4;
    atomicAdd(dst + 0, r.x);
    atomicAdd(dst + 1, r.y);
    atomicAdd(dst + 2, r.z);
    atomicAdd(dst + 3, r.w);
}

// result[b,o] = sum_h W[o,h] * vbar[b,h]. One wave per o; b-range split across 2 blocks.
__global__ __launch_bounds__(256, 4) void k_result(const float4* __restrict__ W4,
                                                   const float4* __restrict__ vbar4,
                                                   float* __restrict__ result) {
    int t = threadIdx.x;
    int lane = t & 63, wave = t >> 6;
    int o  = (blockIdx.x & 255) * 4 + wave;   // [0,1024)
    int b0 = (blockIdx.x >> 8) * 16;          // 0 or 16
    float4 w[4];
    #pragma unroll
    for (int i = 0; i < 4; ++i)
        w[i] = W4[o * 256 + lane + 64 * i];
    for (int b = b0; b < b0 + 16; b += 2) {
        float acc0 = 0.f, acc1 = 0.f;
        #pragma unroll
        for (int i = 0; i < 4; ++i) {
            float4 v0 = vbar4[b * 256 + lane + 64 * i];
            acc0 += v0.x * w[i].x + v0.y * w[i].y + v0.z * w[i].z + v0.w * w[i].w;
            float4 v1 = vbar4[(b + 1) * 256 + lane + 64 * i];
            acc1 += v1.x * w[i].x + v1.y * w[i].y + v1.z * w[i].z + v1.w * w[i].w;
        }
        #pragma unroll
        for (int off = 32; off > 0; off >>= 1) {
            acc0 += __shfl_down(acc0, off, 64);
            acc1 += __shfl_down(acc1, off, 64);
        }
        if (lane == 0) {
            result[b * HDIM + o]       = acc0;
            result[(b + 1) * HDIM + o] = acc1;
        }
    }
}

extern "C" void kernel_launch(void* const* d_in, const int* in_sizes, int n_in,
                              void* d_out, int out_size, void* d_ws, size_t ws_size,
                              hipStream_t stream) {
    const float* query = (const float*)d_in[0];
    const float* key   = (const float*)d_in[1];
    const float* value = (const float*)d_in[2];
    const float* W     = (const float*)d_in[3];
    const float* mlp_w = (const float*)d_in[4];
    const float* mlp_b = (const float*)d_in[5];

    float* out    = (float*)d_out;
    float* result = out;                 // B*H
    float* score  = out + BDIM * LDIM;   // B*L

    float* u1     = (float*)d_ws;
    float* u2     = u1 + HDIM;
    float* vbar   = u2 + HDIM;           // B*H
    float* logits = vbar + BDIM * HDIM;  // B*L

    hipMemsetAsync(d_ws, 0, (size_t)(2 * HDIM + BDIM * HDIM) * sizeof(float), stream);

    k_u12<<<64, 256, 0, stream>>>((const float4*)W, mlp_w, u1, u2);
    k_logits<<<1024, 256, 0, stream>>>((const float4*)query, (const float4*)key,
                                       (const float4*)u1, (const float4*)u2, mlp_b, logits);
    k_softmax<<<BDIM, 256, 0, stream>>>(logits, score);
    k_vbar<<<BDIM * 16, 256, 0, stream>>>((const float4*)value, score, vbar);
    k_result<<<512, 256, 0, stream>>>((const float4*)W, (const float4*)vbar, out);
}

// Round 2
// 375.338 us; speedup vs baseline: 1.0130x; 1.0093x over previous
//
#include <hip/hip_runtime.h>

#define HDIM 1024
#define BDIM 32
#define LDIM 1024

// ws layout (floats): u1[0:H], u2[H:2H], vbar[2H : 2H+B*H], logits[2H+B*H : +B*L]

__device__ __forceinline__ float dot4(float4 a, float4 b) {
    return a.x * b.x + a.y * b.y + a.z * b.z + a.w * b.w;
}

// u1[h] = sum_o W[o,h]*w1[o]; u2[h] = sum_o W[o,h]*w2[o]. Coalesced row reads.
__global__ __launch_bounds__(256) void k_u12(const float4* __restrict__ W4,
                                             const float* __restrict__ mlp_w,
                                             float* __restrict__ u1,
                                             float* __restrict__ u2) {
    int t  = threadIdx.x;            // float4 index within a row, [0,256)
    int o0 = blockIdx.x * 16;        // 64 blocks x 16 rows
    float4 s1 = make_float4(0.f, 0.f, 0.f, 0.f);
    float4 s2 = make_float4(0.f, 0.f, 0.f, 0.f);
    #pragma unroll 4
    for (int o = o0; o < o0 + 16; ++o) {
        float4 w = W4[o * 256 + t];
        float c1 = mlp_w[o];
        float c2 = mlp_w[HDIM + o];
        s1.x += w.x * c1; s1.y += w.y * c1; s1.z += w.z * c1; s1.w += w.w * c1;
        s2.x += w.x * c2; s2.y += w.y * c2; s2.z += w.z * c2; s2.w += w.w * c2;
    }
    int h = t * 4;
    atomicAdd(&u1[h + 0], s1.x); atomicAdd(&u1[h + 1], s1.y);
    atomicAdd(&u1[h + 2], s1.z); atomicAdd(&u1[h + 3], s1.w);
    atomicAdd(&u2[h + 0], s2.x); atomicAdd(&u2[h + 1], s2.y);
    atomicAdd(&u2[h + 2], s2.z); atomicAdd(&u2[h + 3], s2.w);
}

// logits[row] = relu(q[row]·u1 + k[row]·u2 + b).
// Copy-shaped: block owns 8 rows, thread owns ONE float4 slice per row.
// Low VGPR (a1/a2 are single float4s) -> 32 waves/CU; grid 4096 blocks.
__global__ __launch_bounds__(256, 8) void k_logits(const float4* __restrict__ q,
                                                   const float4* __restrict__ k,
                                                   const float4* __restrict__ u1v,
                                                   const float4* __restrict__ u2v,
                                                   const float* __restrict__ mlp_b,
                                                   float* __restrict__ logits) {
    __shared__ float sm[8][4];
    int t = threadIdx.x;
    int lane = t & 63, wave = t >> 6;
    float4 a1 = u1v[t];
    float4 a2 = u2v[t];
    long long r0 = (long long)blockIdx.x * 8;    // [0, 32768) step 8
    const float4* qb = q + r0 * 256 + t;
    const float4* kb = k + r0 * 256 + t;

    float p[8];
    #pragma unroll
    for (int r = 0; r < 8; r += 2) {
        // 4 loads batched per 2-row step; full unroll lets the compiler
        // pipeline up to the 64-VGPR cap.
        float4 xq0 = qb[(r + 0) * 256];
        float4 xk0 = kb[(r + 0) * 256];
        float4 xq1 = qb[(r + 1) * 256];
        float4 xk1 = kb[(r + 1) * 256];
        p[r + 0] = dot4(xq0, a1) + dot4(xk0, a2);
        p[r + 1] = dot4(xq1, a1) + dot4(xk1, a2);
    }
    // 8 independent reduce chains, stage-major so they pipeline
    #pragma unroll
    for (int off = 32; off > 0; off >>= 1)
        #pragma unroll
        for (int r = 0; r < 8; ++r)
            p[r] += __shfl_down(p[r], off, 64);
    if (lane == 0) {
        #pragma unroll
        for (int r = 0; r < 8; ++r)
            sm[r][wave] = p[r];
    }
    __syncthreads();
    if (t < 8) {
        float v = sm[t][0] + sm[t][1] + sm[t][2] + sm[t][3] + mlp_b[0];
        logits[r0 + t] = v > 0.f ? v : 0.f;
    }
}

__global__ __launch_bounds__(256) void k_softmax(const float* __restrict__ logits,
                                                 float* __restrict__ score) {
    __shared__ float sm[4];
    __shared__ float ss[4];
    int b = blockIdx.x;
    int t = threadIdx.x;
    int wave = t >> 6, lane = t & 63;
    float4 v = ((const float4*)(logits + b * LDIM))[t];
    float m = fmaxf(fmaxf(v.x, v.y), fmaxf(v.z, v.w));
    #pragma unroll
    for (int off = 32; off > 0; off >>= 1)
        m = fmaxf(m, __shfl_down(m, off, 64));
    if (lane == 0) sm[wave] = m;
    __syncthreads();
    float M = fmaxf(fmaxf(sm[0], sm[1]), fmaxf(sm[2], sm[3]));
    float4 e;
    e.x = __expf(v.x - M); e.y = __expf(v.y - M);
    e.z = __expf(v.z - M); e.w = __expf(v.w - M);
    float s = e.x + e.y + e.z + e.w;
    #pragma unroll
    for (int off = 32; off > 0; off >>= 1)
        s += __shfl_down(s, off, 64);
    if (lane == 0) ss[wave] = s;
    __syncthreads();
    float inv = 1.f / (ss[0] + ss[1] + ss[2] + ss[3]);
    float4 o;
    o.x = e.x * inv; o.y = e.y * inv; o.z = e.z * inv; o.w = e.w * inv;
    ((float4*)(score + b * LDIM))[t] = o;
}

// vbar[b,h] = sum_l score[b,l] * value[b,l,h].
// Grid 2048: (b, h-chunk of 256 floats, l-slice of 64 rows). Wave owns an
// l-stripe; lane owns one float4 of h. LDS cross-wave reduce, then 4 atomics
// per lane of wave 0 (8 writer-blocks per address).
__global__ __launch_bounds__(256, 8) void k_vbar(const float4* __restrict__ value,
                                                 const float* __restrict__ score,
                                                 float* __restrict__ vbar) {
    __shared__ float4 red[3][64];
    int bid = blockIdx.x;
    int b  = bid >> 6;           // [0,32)
    int hc = (bid >> 4) & 3;     // [0,4)
    int ls = bid & 15;           // [0,16) l-slices of 64 rows
    int t = threadIdx.x, lane = t & 63, wave = t >> 6;
    const float4* vb = value + ((long long)(b * LDIM + ls * 64) * 256) + hc * 64 + lane;
    const float*  sc = score + b * LDIM + ls * 64;
    float4 acc = make_float4(0.f, 0.f, 0.f, 0.f);
    // wave handles l = wave, wave+4, ..., 64 -> 16 rows; batch 4 loads
    #pragma unroll 1
    for (int j = 0; j < 16; j += 4) {
        int l0 = wave + 4 * (j + 0);
        int l1 = wave + 4 * (j + 1);
        int l2 = wave + 4 * (j + 2);
        int l3 = wave + 4 * (j + 3);
        float4 v0 = vb[l0 * 256];
        float4 v1 = vb[l1 * 256];
        float4 v2 = vb[l2 * 256];
        float4 v3 = vb[l3 * 256];
        float s0 = sc[l0], s1 = sc[l1], s2 = sc[l2], s3 = sc[l3];
        acc.x += s0 * v0.x + s1 * v1.x + s2 * v2.x + s3 * v3.x;
        acc.y += s0 * v0.y + s1 * v1.y + s2 * v2.y + s3 * v3.y;
        acc.z += s0 * v0.z + s1 * v1.z + s2 * v2.z + s3 * v3.z;
        acc.w += s0 * v0.w + s1 * v1.w + s2 * v2.w + s3 * v3.w;
    }
    if (wave > 0) red[wave - 1][lane] = acc;
    __syncthreads();
    if (wave == 0) {
        float4 r0 = red[0][lane], r1 = red[1][lane], r2 = red[2][lane];
        acc.x += r0.x + r1.x + r2.x;
        acc.y += r0.y + r1.y + r2.y;
        acc.z += r0.z + r1.z + r2.z;
        acc.w += r0.w + r1.w + r2.w;
        float* dst = vbar + b * HDIM + hc * 256 + lane * 4;
        atomicAdd(dst + 0, acc.x);
        atomicAdd(dst + 1, acc.y);
        atomicAdd(dst + 2, acc.z);
        atomicAdd(dst + 3, acc.w);
    }
}

// result[b,o] = sum_h W[o,h] * vbar[b,h]. One wave per o; b-range split across 2 blocks.
__global__ __launch_bounds__(256, 4) void k_result(const float4* __restrict__ W4,
                                                   const float4* __restrict__ vbar4,
                                                   float* __restrict__ result) {
    int t = threadIdx.x;
    int lane = t & 63, wave = t >> 6;
    int o  = (blockIdx.x & 255) * 4 + wave;   // [0,1024)
    int b0 = (blockIdx.x >> 8) * 16;          // 0 or 16
    float4 w[4];
    #pragma unroll
    for (int i = 0; i < 4; ++i)
        w[i] = W4[o * 256 + lane + 64 * i];
    for (int b = b0; b < b0 + 16; b += 2) {
        float acc0 = 0.f, acc1 = 0.f;
        #pragma unroll
        for (int i = 0; i < 4; ++i) {
            float4 v0 = vbar4[b * 256 + lane + 64 * i];
            acc0 += v0.x * w[i].x + v0.y * w[i].y + v0.z * w[i].z + v0.w * w[i].w;
            float4 v1 = vbar4[(b + 1) * 256 + lane + 64 * i];
            acc1 += v1.x * w[i].x + v1.y * w[i].y + v1.z * w[i].z + v1.w * w[i].w;
        }
        #pragma unroll
        for (int off = 32; off > 0; off >>= 1) {
            acc0 += __shfl_down(acc0, off, 64);
            acc1 += __shfl_down(acc1, off, 64);
        }
        if (lane == 0) {
            result[b * HDIM + o]       = acc0;
            result[(b + 1) * HDIM + o] = acc1;
        }
    }
}

extern "C" void kernel_launch(void* const* d_in, const int* in_sizes, int n_in,
                              void* d_out, int out_size, void* d_ws, size_t ws_size,
                              hipStream_t stream) {
    const float* query = (const float*)d_in[0];
    const float* key   = (const float*)d_in[1];
    const float* value = (const float*)d_in[2];
    const float* W     = (const float*)d_in[3];
    const float* mlp_w = (const float*)d_in[4];
    const float* mlp_b = (const float*)d_in[5];

    float* out    = (float*)d_out;
    float* result = out;                 // B*H
    float* score  = out + BDIM * LDIM;   // B*L

    float* u1     = (float*)d_ws;
    float* u2     = u1 + HDIM;
    float* vbar   = u2 + HDIM;           // B*H
    float* logits = vbar + BDIM * HDIM;  // B*L

    hipMemsetAsync(d_ws, 0, (size_t)(2 * HDIM + BDIM * HDIM) * sizeof(float), stream);

    k_u12<<<64, 256, 0, stream>>>((const float4*)W, mlp_w, u1, u2);
    k_logits<<<4096, 256, 0, stream>>>((const float4*)query, (const float4*)key,
                                       (const float4*)u1, (const float4*)u2, mlp_b, logits);
    k_softmax<<<BDIM, 256, 0, stream>>>(logits, score);
    k_vbar<<<2048, 256, 0, stream>>>((const float4*)value, score, vbar);
    k_result<<<512, 256, 0, stream>>>((const float4*)W, (const float4*)vbar, out);
}

// Round 5
// 348.471 us; speedup vs baseline: 1.0911x; 1.0771x over previous
//
#include <hip/hip_runtime.h>

#define HDIM 1024
#define BDIM 32
#define LDIM 1024

// ws layout (floats): u1[0:H], u2[H:2H], vbar[2H : 2H+B*H], logits[2H+B*H : +B*L]

typedef float vfloat4 __attribute__((ext_vector_type(4)));

__device__ __forceinline__ float dot4(float4 a, float4 b) {
    return a.x * b.x + a.y * b.y + a.z * b.z + a.w * b.w;
}

__device__ __forceinline__ float4 ntload4(const float4* p) {
    vfloat4 v = __builtin_nontemporal_load((const vfloat4*)p);
    return make_float4(v.x, v.y, v.z, v.w);
}

// u1[h] = sum_o W[o,h]*w1[o]; u2[h] = sum_o W[o,h]*w2[o]. Coalesced row reads.
__global__ __launch_bounds__(256) void k_u12(const float4* __restrict__ W4,
                                             const float* __restrict__ mlp_w,
                                             float* __restrict__ u1,
                                             float* __restrict__ u2) {
    int t  = threadIdx.x;            // float4 index within a row, [0,256)
    int o0 = blockIdx.x * 16;        // 64 blocks x 16 rows
    float4 s1 = make_float4(0.f, 0.f, 0.f, 0.f);
    float4 s2 = make_float4(0.f, 0.f, 0.f, 0.f);
    #pragma unroll 4
    for (int o = o0; o < o0 + 16; ++o) {
        float4 w = W4[o * 256 + t];
        float c1 = mlp_w[o];
        float c2 = mlp_w[HDIM + o];
        s1.x += w.x * c1; s1.y += w.y * c1; s1.z += w.z * c1; s1.w += w.w * c1;
        s2.x += w.x * c2; s2.y += w.y * c2; s2.z += w.z * c2; s2.w += w.w * c2;
    }
    int h = t * 4;
    atomicAdd(&u1[h + 0], s1.x); atomicAdd(&u1[h + 1], s1.y);
    atomicAdd(&u1[h + 2], s1.z); atomicAdd(&u1[h + 3], s1.w);
    atomicAdd(&u2[h + 0], s2.x); atomicAdd(&u2[h + 1], s2.y);
    atomicAdd(&u2[h + 2], s2.z); atomicAdd(&u2[h + 3], s2.w);
}

// logits[row] = relu(q[row]·u1 + k[row]·u2 + b).
// Block spans the row across its 4 waves (t = float4 index in [0,256)),
// so each wave's shuffle-reduce is a QUARTER dot -> must combine across
// waves in LDS (double-buffered per grid-stride group).
__global__ __launch_bounds__(256) void k_logits(const float4* __restrict__ q,
                                                const float4* __restrict__ k,
                                                const float4* __restrict__ u1v,
                                                const float4* __restrict__ u2v,
                                                const float* __restrict__ mlp_b,
                                                float* __restrict__ logits) {
    __shared__ float sm[2][8][4];
    int t = threadIdx.x;
    int lane = t & 63, wave = t >> 6;
    float4 a1 = u1v[t];
    float4 a2 = u2v[t];
    float bias = mlp_b[0];
    #pragma unroll 1
    for (int g = 0; g < 2; ++g) {
        long long grp = (long long)blockIdx.x + 2048LL * g;   // [0, 4096)
        long long r0  = grp * 8;                              // row base
        const float4* qb = q + r0 * 256 + t;
        const float4* kb = k + r0 * 256 + t;
        float p[8];
        float4 xq[4], xk[4];
        // rows 0..3: 8 loads in flight
        #pragma unroll
        for (int r = 0; r < 4; ++r) xq[r] = ntload4(qb + r * 256);
        #pragma unroll
        for (int r = 0; r < 4; ++r) xk[r] = ntload4(kb + r * 256);
        #pragma unroll
        for (int r = 0; r < 4; ++r) p[r] = dot4(xq[r], a1) + dot4(xk[r], a2);
        // rows 4..7
        #pragma unroll
        for (int r = 0; r < 4; ++r) xq[r] = ntload4(qb + (4 + r) * 256);
        #pragma unroll
        for (int r = 0; r < 4; ++r) xk[r] = ntload4(kb + (4 + r) * 256);
        #pragma unroll
        for (int r = 0; r < 4; ++r) p[4 + r] = dot4(xq[r], a1) + dot4(xk[r], a2);
        // 8 independent reduce chains, stage-major so they pipeline
        #pragma unroll
        for (int off = 32; off > 0; off >>= 1)
            #pragma unroll
            for (int r = 0; r < 8; ++r)
                p[r] += __shfl_down(p[r], off, 64);
        if (lane == 0) {
            #pragma unroll
            for (int r = 0; r < 8; ++r)
                sm[g][r][wave] = p[r];
        }
        __syncthreads();
        if (t < 8) {
            float v = sm[g][t][0] + sm[g][t][1] + sm[g][t][2] + sm[g][t][3] + bias;
            logits[r0 + t] = v > 0.f ? v : 0.f;
        }
    }
}

__global__ __launch_bounds__(256) void k_softmax(const float* __restrict__ logits,
                                                 float* __restrict__ score) {
    __shared__ float sm[4];
    __shared__ float ss[4];
    int b = blockIdx.x;
    int t = threadIdx.x;
    int wave = t >> 6, lane = t & 63;
    float4 v = ((const float4*)(logits + b * LDIM))[t];
    float m = fmaxf(fmaxf(v.x, v.y), fmaxf(v.z, v.w));
    #pragma unroll
    for (int off = 32; off > 0; off >>= 1)
        m = fmaxf(m, __shfl_down(m, off, 64));
    if (lane == 0) sm[wave] = m;
    __syncthreads();
    float M = fmaxf(fmaxf(sm[0], sm[1]), fmaxf(sm[2], sm[3]));
    float4 e;
    e.x = __expf(v.x - M); e.y = __expf(v.y - M);
    e.z = __expf(v.z - M); e.w = __expf(v.w - M);
    float s = e.x + e.y + e.z + e.w;
    #pragma unroll
    for (int off = 32; off > 0; off >>= 1)
        s += __shfl_down(s, off, 64);
    if (lane == 0) ss[wave] = s;
    __syncthreads();
    float inv = 1.f / (ss[0] + ss[1] + ss[2] + ss[3]);
    float4 o;
    o.x = e.x * inv; o.y = e.y * inv; o.z = e.z * inv; o.w = e.w * inv;
    ((float4*)(score + b * LDIM))[t] = o;
}

// vbar[b,h] = sum_l score[b,l] * value[b,l,h].
// Grid 2048: (b, h-chunk of 256 floats, l-slice of 64 rows). Wave owns an
// l-stripe (l == wave mod 4); 8 nontemporal loads in flight; LDS cross-wave
// reduce; 4 atomics per lane of wave 0.
__global__ __launch_bounds__(256) void k_vbar(const float4* __restrict__ value,
                                              const float* __restrict__ score,
                                              float* __restrict__ vbar) {
    __shared__ float4 red[3][64];
    int bid = blockIdx.x;
    int b  = bid >> 6;           // [0,32)
    int hc = (bid >> 4) & 3;     // [0,4)
    int ls = bid & 15;           // [0,16) l-slices of 64 rows
    int t = threadIdx.x, lane = t & 63, wave = t >> 6;
    const float4* vb = value + ((long long)(b * LDIM + ls * 64) * 256) + hc * 64 + lane;
    const float*  sc = score + b * LDIM + ls * 64;
    float4 acc = make_float4(0.f, 0.f, 0.f, 0.f);
    // wave handles l = wave + 4*i, i in [0,16); two batches of 8
    #pragma unroll 1
    for (int j = 0; j < 2; ++j) {
        int i0 = j * 8;
        float4 v0 = ntload4(vb + (wave + 4 * (i0 + 0)) * 256);
        float4 v1 = ntload4(vb + (wave + 4 * (i0 + 1)) * 256);
        float4 v2 = ntload4(vb + (wave + 4 * (i0 + 2)) * 256);
        float4 v3 = ntload4(vb + (wave + 4 * (i0 + 3)) * 256);
        float4 v4 = ntload4(vb + (wave + 4 * (i0 + 4)) * 256);
        float4 v5 = ntload4(vb + (wave + 4 * (i0 + 5)) * 256);
        float4 v6 = ntload4(vb + (wave + 4 * (i0 + 6)) * 256);
        float4 v7 = ntload4(vb + (wave + 4 * (i0 + 7)) * 256);
        float s0 = sc[wave + 4 * (i0 + 0)];
        float s1 = sc[wave + 4 * (i0 + 1)];
        float s2 = sc[wave + 4 * (i0 + 2)];
        float s3 = sc[wave + 4 * (i0 + 3)];
        float s4 = sc[wave + 4 * (i0 + 4)];
        float s5 = sc[wave + 4 * (i0 + 5)];
        float s6 = sc[wave + 4 * (i0 + 6)];
        float s7 = sc[wave + 4 * (i0 + 7)];
        acc.x += s0 * v0.x + s1 * v1.x + s2 * v2.x + s3 * v3.x
               + s4 * v4.x + s5 * v5.x + s6 * v6.x + s7 * v7.x;
        acc.y += s0 * v0.y + s1 * v1.y + s2 * v2.y + s3 * v3.y
               + s4 * v4.y + s5 * v5.y + s6 * v6.y + s7 * v7.y;
        acc.z += s0 * v0.z + s1 * v1.z + s2 * v2.z + s3 * v3.z
               + s4 * v4.z + s5 * v5.z + s6 * v6.z + s7 * v7.z;
        acc.w += s0 * v0.w + s1 * v1.w + s2 * v2.w + s3 * v3.w
               + s4 * v4.w + s5 * v5.w + s6 * v6.w + s7 * v7.w;
    }
    if (wave > 0) red[wave - 1][lane] = acc;
    __syncthreads();
    if (wave == 0) {
        float4 r0 = red[0][lane], r1 = red[1][lane], r2 = red[2][lane];
        acc.x += r0.x + r1.x + r2.x;
        acc.y += r0.y + r1.y + r2.y;
        acc.z += r0.z + r1.z + r2.z;
        acc.w += r0.w + r1.w + r2.w;
        float* dst = vbar + b * HDIM + hc * 256 + lane * 4;
        atomicAdd(dst + 0, acc.x);
        atomicAdd(dst + 1, acc.y);
        atomicAdd(dst + 2, acc.z);
        atomicAdd(dst + 3, acc.w);
    }
}

// result[b,o] = sum_h W[o,h] * vbar[b,h]. One wave per o; b-range split 4-way.
__global__ __launch_bounds__(256) void k_result(const float4* __restrict__ W4,
                                                const float4* __restrict__ vbar4,
                                                float* __restrict__ result) {
    int t = threadIdx.x;
    int lane = t & 63, wave = t >> 6;
    int o  = (blockIdx.x & 255) * 4 + wave;   // [0,1024)
    int b0 = (blockIdx.x >> 8) * 8;           // {0,8,16,24}
    float4 w[4];
    #pragma unroll
    for (int i = 0; i < 4; ++i)
        w[i] = W4[o * 256 + lane + 64 * i];
    for (int b = b0; b < b0 + 8; b += 2) {
        float acc0 = 0.f, acc1 = 0.f;
        #pragma unroll
        for (int i = 0; i < 4; ++i) {
            float4 v0 = vbar4[b * 256 + lane + 64 * i];
            acc0 += v0.x * w[i].x + v0.y * w[i].y + v0.z * w[i].z + v0.w * w[i].w;
            float4 v1 = vbar4[(b + 1) * 256 + lane + 64 * i];
            acc1 += v1.x * w[i].x + v1.y * w[i].y + v1.z * w[i].z + v1.w * w[i].w;
        }
        #pragma unroll
        for (int off = 32; off > 0; off >>= 1) {
            acc0 += __shfl_down(acc0, off, 64);
            acc1 += __shfl_down(acc1, off, 64);
        }
        if (lane == 0) {
            result[b * HDIM + o]       = acc0;
            result[(b + 1) * HDIM + o] = acc1;
        }
    }
}

extern "C" void kernel_launch(void* const* d_in, const int* in_sizes, int n_in,
                              void* d_out, int out_size, void* d_ws, size_t ws_size,
                              hipStream_t stream) {
    const float* query = (const float*)d_in[0];
    const float* key   = (const float*)d_in[1];
    const float* value = (const float*)d_in[2];
    const float* W     = (const float*)d_in[3];
    const float* mlp_w = (const float*)d_in[4];
    const float* mlp_b = (const float*)d_in[5];

    float* out    = (float*)d_out;
    float* result = out;                 // B*H
    float* score  = out + BDIM * LDIM;   // B*L

    float* u1     = (float*)d_ws;
    float* u2     = u1 + HDIM;
    float* vbar   = u2 + HDIM;           // B*H
    float* logits = vbar + BDIM * HDIM;  // B*L

    hipMemsetAsync(d_ws, 0, (size_t)(2 * HDIM + BDIM * HDIM) * sizeof(float), stream);

    k_u12<<<64, 256, 0, stream>>>((const float4*)W, mlp_w, u1, u2);
    k_logits<<<2048, 256, 0, stream>>>((const float4*)query, (const float4*)key,
                                       (const float4*)u1, (const float4*)u2, mlp_b, logits);
    k_softmax<<<BDIM, 256, 0, stream>>>(logits, score);
    k_vbar<<<2048, 256, 0, stream>>>((const float4*)value, score, vbar);
    k_result<<<1024, 256, 0, stream>>>((const float4*)W, (const float4*)vbar, out);
}